// Round 4
// baseline (133.551 us; speedup 1.0000x reference)
//
#include <hip/hip_runtime.h>
#include <hip/hip_cooperative_groups.h>

namespace cg = cooperative_groups;

#define NUM_CLASSES 80
#define CH 85            // channels per anchor in add_sigmoid
#define BATCH 16
#define BLOCK 256
#define NUM_CU 256       // MI355X

// Single cooperative kernel: dense conf BCE + wave-cooperative fore terms,
// block partials -> grid.sync -> block 0 finalizes. No atomics, no memsets.
__global__ void __launch_bounds__(BLOCK)
multibox_coop(const float* __restrict__ add_sigmoid,
              const float* __restrict__ loc_t,
              const float* __restrict__ conf_t,
              const float* __restrict__ scale_t,
              const int*   __restrict__ cls_t,
              const unsigned char* __restrict__ fore_m,
              const unsigned char* __restrict__ back_m,
              float* __restrict__ partials,
              float* __restrict__ out,
              int n, int ntiles)
{
    // mask dtype detection: numpy bool (1B) vs int32 (4B). back = !fore, so
    // u8 storage has fore^back == 1 at byte offsets 1..3; i32 storage has 0s.
    const bool is_u8 =
        (((fore_m[1] ^ back_m[1]) | (fore_m[2] ^ back_m[2]) | (fore_m[3] ^ back_m[3])) & 1) != 0;
    const int* fore_i32 = (const int*)fore_m;

    const int lane = threadIdx.x & 63;
    float acc = 0.f;

    for (int tile = blockIdx.x; tile < ntiles; tile += gridDim.x) {
        const int i = tile * BLOCK + threadIdx.x;
        bool fore_b = false;
        if (i < n) {
            fore_b = is_u8 ? (fore_m[i] != 0) : (fore_i32[i] != 0);
            // conf BCE: fore + back == 1 for every anchor
            const float cp = add_sigmoid[(size_t)i * CH + 4];
            const float t  = conf_t[i];
            acc -= t * __logf(cp) + (1.f - t) * __logf(1.f - cp);
        }

        // ---- wave-cooperative fore anchors, 2 at a time for MLP ----
        unsigned long long m = __ballot(fore_b);
        while (m) {
            const int s0 = (int)__ffsll((long long)m) - 1;
            m &= m - 1;
            int s1 = -1;
            if (m) { s1 = (int)__ffsll((long long)m) - 1; m &= m - 1; }
            const bool v1 = (s1 >= 0);

            const int ia0 = __shfl(i, s0, 64);
            const int ia1 = __shfl(i, v1 ? s1 : s0, 64);

            const float* b0 = add_sigmoid + (size_t)ia0 * CH;
            const float* b1 = add_sigmoid + (size_t)ia1 * CH;

            // issue all independent loads up front
            const float p0 = b0[lane];
            const float p1 = b1[lane];
            float q0 = 0.5f, q1 = 0.5f;
            if (lane < CH - 64) { q0 = b0[lane + 64]; q1 = b1[lane + 64]; }
            const int   k0 = cls_t[ia0],   k1 = cls_t[ia1];
            const float w0 = scale_t[ia0], w1 = scale_t[ia1];
            float l0 = 0.f, l1 = 0.f;
            if (lane < 4) { l0 = loc_t[4 * (size_t)ia0 + lane];
                            l1 = loc_t[4 * (size_t)ia1 + lane]; }

            float c0 = 0.f, c1 = 0.f;
            if (lane < 4) {
                const float d0 = l0 - p0, d1 = l1 - p1;
                c0 = w0 * 0.5f * d0 * d0;
                c1 = w1 * 0.5f * d1 * d1;
            } else if (lane >= 5) {       // classes 0..58
                c0 = (lane - 5 == k0) ? -__logf(p0) : -__logf(1.f - p0);
                c1 = (lane - 5 == k1) ? -__logf(p1) : -__logf(1.f - p1);
            }
            if (lane < CH - 64) {         // classes 59..79
                c0 += (lane + 59 == k0) ? -__logf(q0) : -__logf(1.f - q0);
                c1 += (lane + 59 == k1) ? -__logf(q1) : -__logf(1.f - q1);
            }
            acc += c0;
            acc += v1 ? c1 : 0.f;
        }
    }

    // ---- block reduction -> one partial per block ----
    #pragma unroll
    for (int off = 32; off > 0; off >>= 1)
        acc += __shfl_down(acc, off, 64);
    __shared__ float wsum[BLOCK / 64];
    const int wid = threadIdx.x >> 6;
    if (lane == 0) wsum[wid] = acc;
    __syncthreads();
    if (threadIdx.x == 0)
        partials[blockIdx.x] = wsum[0] + wsum[1] + wsum[2] + wsum[3];

    // ---- grid-wide sync, then block 0 finalizes ----
    cg::this_grid().sync();
    if (blockIdx.x == 0) {
        float s = 0.f;
        for (int j = threadIdx.x; j < gridDim.x; j += BLOCK) s += partials[j];
        #pragma unroll
        for (int off = 32; off > 0; off >>= 1)
            s += __shfl_down(s, off, 64);
        if (lane == 0) wsum[wid] = s;
        __syncthreads();
        if (threadIdx.x == 0)
            out[0] = (wsum[0] + wsum[1] + wsum[2] + wsum[3]) * (1.f / BATCH);
    }
}

extern "C" void kernel_launch(void* const* d_in, const int* in_sizes, int n_in,
                              void* d_out, int out_size, void* d_ws, size_t ws_size,
                              hipStream_t stream) {
    const float* add_sigmoid = (const float*)d_in[0];
    const float* loc_t       = (const float*)d_in[1];
    const float* conf_t      = (const float*)d_in[2];
    const float* scale_t     = (const float*)d_in[3];
    const int*   cls_t       = (const int*)d_in[4];
    const unsigned char* fore_m = (const unsigned char*)d_in[5];
    const unsigned char* back_m = (const unsigned char*)d_in[6];
    float* out = (float*)d_out;

    const int n      = in_sizes[2];                // conf_t count = B*P
    const int ntiles = (n + BLOCK - 1) / BLOCK;

    float* partials = (float*)d_ws;                // grid floats, overwritten each call

    // Clamp grid to co-resident capacity for cooperative launch.
    int nb = 0;
    hipOccupancyMaxActiveBlocksPerMultiprocessor(&nb, (const void*)multibox_coop, BLOCK, 0);
    if (nb < 1) nb = 1;
    int grid = ntiles < nb * NUM_CU ? ntiles : nb * NUM_CU;

    int ntiles_a = ntiles;
    int n_a = n;
    void* args[] = {
        (void*)&add_sigmoid, (void*)&loc_t, (void*)&conf_t, (void*)&scale_t,
        (void*)&cls_t, (void*)&fore_m, (void*)&back_m,
        (void*)&partials, (void*)&out, (void*)&n_a, (void*)&ntiles_a
    };
    hipLaunchCooperativeKernel((const void*)multibox_coop,
                               dim3(grid), dim3(BLOCK), args, 0, stream);
}

// Round 5
// 22.167 us; speedup vs baseline: 6.0247x; 6.0247x over previous
//
#include <hip/hip_runtime.h>

#define NUM_CLASSES 80
#define CH 85            // channels per anchor in add_sigmoid
#define BATCH 16
#define BLOCK 256
#define G 2              // anchors per thread (independent gathers for ILP)

// ---------- Kernel 1: dense conf BCE + wave-cooperative fore terms ----------
__global__ void __launch_bounds__(BLOCK)
multibox_main(const float* __restrict__ add_sigmoid,
              const float* __restrict__ loc_t,
              const float* __restrict__ conf_t,
              const float* __restrict__ scale_t,
              const int*   __restrict__ cls_t,
              const unsigned char* __restrict__ fore_m,
              const unsigned char* __restrict__ back_m,
              float* __restrict__ partials,
              int n)
{
    // mask dtype detection: numpy bool (1B) vs int32 (4B). back = !fore, so
    // u8 storage has fore^back == 1 at byte offsets 1..3; i32 storage has 0s.
    const bool is_u8 =
        (((fore_m[1] ^ back_m[1]) | (fore_m[2] ^ back_m[2]) | (fore_m[3] ^ back_m[3])) & 1) != 0;
    const int* fore_i32 = (const int*)fore_m;

    const int lane = threadIdx.x & 63;
    const int i0   = blockIdx.x * (BLOCK * G) + threadIdx.x;

    // ---- issue all independent scattered loads up front (ILP across G) ----
    int   ia[G];
    bool  valid[G], fore_b[G];
    float cp[G], t[G];
    #pragma unroll
    for (int j = 0; j < G; ++j) {
        ia[j]    = i0 + j * BLOCK;
        valid[j] = ia[j] < n;
        const int ic = valid[j] ? ia[j] : 0;
        fore_b[j] = valid[j] &&
                    (is_u8 ? (fore_m[ic] != 0) : (fore_i32[ic] != 0));
        cp[j] = add_sigmoid[(size_t)ic * CH + 4];   // scattered gather
        t[j]  = conf_t[ic];                         // coalesced
    }

    float acc = 0.f;
    #pragma unroll
    for (int j = 0; j < G; ++j) {
        if (valid[j])
            acc -= t[j] * __logf(cp[j]) + (1.f - t[j]) * __logf(1.f - cp[j]);
    }

    // ---- wave-cooperative fore anchors (R3-proven one-at-a-time loop) ----
    #pragma unroll
    for (int j = 0; j < G; ++j) {
        unsigned long long m = __ballot(fore_b[j]);
        while (m) {
            const int src = (int)__ffsll((long long)m) - 1;
            m &= m - 1;
            const int a = __shfl(ia[j], src, 64);     // anchor owned by lane src
            const float* base = add_sigmoid + (size_t)a * CH;
            const int k = cls_t[a];                   // broadcast load

            float c = 0.f;
            const float p = base[lane];               // channels 0..63
            if (lane < 4) {
                const float d = loc_t[4 * (size_t)a + lane] - p;
                c = scale_t[a] * 0.5f * d * d;
            } else if (lane >= 5) {                   // classes 0..58
                c = (lane - 5 == k) ? -__logf(p) : -__logf(1.f - p);
            }
            if (lane < CH - 64) {                     // channels 64..84 -> classes 59..79
                const float p2 = base[lane + 64];
                c += (lane + 59 == k) ? -__logf(p2) : -__logf(1.f - p2);
            }
            acc += c;
        }
    }

    // ---- block reduction -> one partial per block, no atomics ----
    #pragma unroll
    for (int off = 32; off > 0; off >>= 1)
        acc += __shfl_down(acc, off, 64);
    __shared__ float wsum[BLOCK / 64];
    const int wid = threadIdx.x >> 6;
    if (lane == 0) wsum[wid] = acc;
    __syncthreads();
    if (threadIdx.x == 0)
        partials[blockIdx.x] = wsum[0] + wsum[1] + wsum[2] + wsum[3];
}

// ---------- Kernel 2: single-block finalize ----------
__global__ void __launch_bounds__(BLOCK)
multibox_finalize(const float* __restrict__ partials, float* __restrict__ out, int g)
{
    float acc = 0.f;
    for (int j = threadIdx.x; j < g; j += BLOCK) acc += partials[j];
    #pragma unroll
    for (int off = 32; off > 0; off >>= 1)
        acc += __shfl_down(acc, off, 64);
    __shared__ float wsum[BLOCK / 64];
    const int lane = threadIdx.x & 63, wid = threadIdx.x >> 6;
    if (lane == 0) wsum[wid] = acc;
    __syncthreads();
    if (threadIdx.x == 0)
        out[0] = (wsum[0] + wsum[1] + wsum[2] + wsum[3]) * (1.f / BATCH);
}

extern "C" void kernel_launch(void* const* d_in, const int* in_sizes, int n_in,
                              void* d_out, int out_size, void* d_ws, size_t ws_size,
                              hipStream_t stream) {
    const float* add_sigmoid = (const float*)d_in[0];
    const float* loc_t       = (const float*)d_in[1];
    const float* conf_t      = (const float*)d_in[2];
    const float* scale_t     = (const float*)d_in[3];
    const int*   cls_t       = (const int*)d_in[4];
    const unsigned char* fore_m = (const unsigned char*)d_in[5];
    const unsigned char* back_m = (const unsigned char*)d_in[6];
    float* out = (float*)d_out;

    const int n    = in_sizes[2];                  // conf_t count = B*P
    const int grid = (n + BLOCK * G - 1) / (BLOCK * G);

    float* partials = (float*)d_ws;                // grid floats, overwritten each call

    multibox_main<<<grid, BLOCK, 0, stream>>>(
        add_sigmoid, loc_t, conf_t, scale_t, cls_t, fore_m, back_m, partials, n);
    multibox_finalize<<<1, BLOCK, 0, stream>>>(partials, out, grid);
}

// Round 7
// 19.917 us; speedup vs baseline: 6.7054x; 1.1130x over previous
//
#include <hip/hip_runtime.h>

#define CH 85            // channels per anchor in add_sigmoid
#define BATCH 16
#define BLOCK 1024       // A/B vs R3: 4x fewer workgroups, SAME wave count
#define FBLOCK 256

// ---------- Kernel 1: dense conf BCE + wave-cooperative fore terms ----------
__global__ void __launch_bounds__(BLOCK)
multibox_main(const float* __restrict__ add_sigmoid,
              const float* __restrict__ loc_t,
              const float* __restrict__ conf_t,
              const float* __restrict__ scale_t,
              const int*   __restrict__ cls_t,
              const unsigned char* __restrict__ fore_m,
              const unsigned char* __restrict__ back_m,
              float* __restrict__ partials,
              int n)
{
    // mask dtype detection: numpy bool (1B) vs int32 (4B). back = !fore, so
    // u8 storage has fore^back == 1 at byte offsets 1..3; i32 storage has 0s.
    const bool is_u8 =
        (((fore_m[1] ^ back_m[1]) | (fore_m[2] ^ back_m[2]) | (fore_m[3] ^ back_m[3])) & 1) != 0;
    const int* fore_i32 = (const int*)fore_m;

    const int i         = blockIdx.x * BLOCK + threadIdx.x;
    const int lane      = threadIdx.x & 63;
    const int wave_base = blockIdx.x * BLOCK + (threadIdx.x & ~63);

    float acc = 0.f;
    bool fore_b = false;
    if (i < n) {
        fore_b = is_u8 ? (fore_m[i] != 0) : (fore_i32[i] != 0);
        // conf BCE (fore + back == 1): -(log1mp + t*(logp - log1mp))
        const float cp  = add_sigmoid[(size_t)i * CH + 4];
        const float t   = conf_t[i];
        const float lp  = __logf(cp);
        const float l1p = __logf(1.f - cp);
        acc = -__builtin_fmaf(t, lp - l1p, l1p);
    }

    // ---- wave-cooperative fore anchors; anchor index by arithmetic, no shfl ----
    unsigned long long m = __ballot(fore_b);
    while (m) {
        const int src = (int)__ffsll((long long)m) - 1;
        m &= m - 1;
        const int a = wave_base + src;            // lane src owns anchor wave_base+src
        const float* base = add_sigmoid + (size_t)a * CH;
        const int k = cls_t[a];                   // broadcast load

        float c = 0.f;
        const float p = base[lane];               // channels 0..63
        if (lane < 4) {
            const float d = loc_t[4 * (size_t)a + lane] - p;
            c = scale_t[a] * 0.5f * d * d;
        } else if (lane >= 5) {                   // classes 0..58
            c = (lane - 5 == k) ? -__logf(p) : -__logf(1.f - p);
        }
        if (lane < CH - 64) {                     // channels 64..84 -> classes 59..79
            const float p2 = base[lane + 64];
            c += (lane + 59 == k) ? -__logf(p2) : -__logf(1.f - p2);
        }
        acc += c;
    }

    // ---- block reduction -> one partial per block ----
    #pragma unroll
    for (int off = 32; off > 0; off >>= 1)
        acc += __shfl_down(acc, off, 64);
    __shared__ float wsum[BLOCK / 64];            // 16 waves
    const int wid = threadIdx.x >> 6;
    if (lane == 0) wsum[wid] = acc;
    __syncthreads();
    if (threadIdx.x == 0) {
        float s = 0.f;
        #pragma unroll
        for (int w = 0; w < BLOCK / 64; ++w) s += wsum[w];
        partials[blockIdx.x] = s;
    }
}

// ---------- Kernel 2: single-block finalize ----------
__global__ void __launch_bounds__(FBLOCK)
multibox_finalize(const float* __restrict__ partials, float* __restrict__ out, int g)
{
    float acc = 0.f;
    for (int j = threadIdx.x; j < g; j += FBLOCK) acc += partials[j];
    #pragma unroll
    for (int off = 32; off > 0; off >>= 1)
        acc += __shfl_down(acc, off, 64);
    __shared__ float wsum[FBLOCK / 64];
    const int lane = threadIdx.x & 63, wid = threadIdx.x >> 6;
    if (lane == 0) wsum[wid] = acc;
    __syncthreads();
    if (threadIdx.x == 0)
        out[0] = (wsum[0] + wsum[1] + wsum[2] + wsum[3]) * (1.f / BATCH);
}

extern "C" void kernel_launch(void* const* d_in, const int* in_sizes, int n_in,
                              void* d_out, int out_size, void* d_ws, size_t ws_size,
                              hipStream_t stream) {
    const float* add_sigmoid = (const float*)d_in[0];
    const float* loc_t       = (const float*)d_in[1];
    const float* conf_t      = (const float*)d_in[2];
    const float* scale_t     = (const float*)d_in[3];
    const int*   cls_t       = (const int*)d_in[4];
    const unsigned char* fore_m = (const unsigned char*)d_in[5];
    const unsigned char* back_m = (const unsigned char*)d_in[6];
    float* out = (float*)d_out;

    const int n    = in_sizes[2];                  // conf_t count = B*P
    const int grid = (n + BLOCK - 1) / BLOCK;      // 356 workgroups, 5696 waves

    float* partials = (float*)d_ws;                // grid floats, overwritten each call

    multibox_main<<<grid, BLOCK, 0, stream>>>(
        add_sigmoid, loc_t, conf_t, scale_t, cls_t, fore_m, back_m, partials, n);
    multibox_finalize<<<1, FBLOCK, 0, stream>>>(partials, out, grid);
}